// Round 8
// baseline (548.535 us; speedup 1.0000x reference)
//
#include <hip/hip_runtime.h>
#include <hip/hip_cooperative_groups.h>

namespace cg = cooperative_groups;

#define N_NODES 50000
#define N_EDGES 600000
#define D 128
#define BUILD_BLOCKS 512
#define BUILD_THREADS (BUILD_BLOCKS * 256)

typedef __attribute__((ext_vector_type(8))) short bf16x8;
typedef __attribute__((ext_vector_type(4))) float floatx4;

__device__ inline unsigned int f2bf(float f) {
    unsigned int u = __float_as_uint(f);
    return (u + 0x7FFFu + ((u >> 16) & 1u)) >> 16;   // RNE
}
__device__ inline float bf_lo(unsigned int u) { return __uint_as_float(u << 16); }
__device__ inline float bf_hi(unsigned int u) { return __uint_as_float(u & 0xFFFF0000u); }

// ---------------- cooperative build: cvt + count + scan + bucket ----------------
// 512 blocks x 256 threads (<=2 blocks/CU, low VGPR/LDS -> co-resident).
__global__ void __launch_bounds__(256) k_build(
    const float* __restrict__ x, unsigned short* __restrict__ xbf,
    const float* __restrict__ wa, const float* __restrict__ wb,
    const float* __restrict__ wc, const float* __restrict__ wd,
    unsigned short* __restrict__ wbf,
    const int* __restrict__ src, const int* __restrict__ dst,
    int* __restrict__ cnt, int* __restrict__ off, int* __restrict__ cursor,
    int* __restrict__ partial, int* __restrict__ ebuf) {
    cg::grid_group grid = cg::this_grid();
    __shared__ int sdata[256];
    const int t = threadIdx.x;
    const int b = blockIdx.x;
    const int gtid = b * 256 + t;

    // phase A: zero cnt, convert x and W to bf16
    for (int i = gtid; i < N_NODES; i += BUILD_THREADS) cnt[i] = 0;
    for (int i = gtid; i < N_NODES * D / 4; i += BUILD_THREADS) {
        float4 v = ((const float4*)x)[i];
        uint2 o;
        o.x = f2bf(v.x) | (f2bf(v.y) << 16);
        o.y = f2bf(v.z) | (f2bf(v.w) << 16);
        ((uint2*)xbf)[i] = o;
    }
    if (gtid < 65536) {
        const float* srcs[4] = {wa, wb, wc, wd};
        wbf[gtid] = (unsigned short)f2bf(srcs[gtid >> 14][gtid & 16383]);
    }
    grid.sync();

    // phase B: degree count
    for (int e = gtid; e < N_EDGES; e += BUILD_THREADS) atomicAdd(&cnt[dst[e]], 1);
    grid.sync();

    // phase C1: block-local scan (node gtid; only blocks 0..195 carry nodes)
    int v = (gtid < N_NODES) ? cnt[gtid] : 0;
    sdata[t] = v;
    __syncthreads();
    for (int d = 1; d < 256; d <<= 1) {
        int u = (t >= d) ? sdata[t - d] : 0;
        __syncthreads();
        sdata[t] += u;
        __syncthreads();
    }
    if (gtid < N_NODES) off[gtid] = sdata[t] - v;  // local exclusive
    if (t == 255) partial[b] = sdata[255];
    grid.sync();

    // phase C2: block 0 exclusive-scans the 512 block totals (pair trick)
    if (b == 0) {
        int p0 = partial[2 * t], p1 = partial[2 * t + 1];
        int pr = p0 + p1;
        sdata[t] = pr;
        __syncthreads();
        for (int d = 1; d < 256; d <<= 1) {
            int u = (t >= d) ? sdata[t - d] : 0;
            __syncthreads();
            sdata[t] += u;
            __syncthreads();
        }
        int excl = sdata[t] - pr;
        partial[2 * t] = excl;
        partial[2 * t + 1] = excl + p0;
    }
    grid.sync();

    // phase C3: final offsets + cursor
    if (gtid < N_NODES) {
        int o = off[gtid] + partial[b];
        off[gtid] = o;
        cursor[gtid] = o;
    }
    if (gtid == 0) off[N_NODES] = N_EDGES;
    grid.sync();

    // phase D: bucket
    for (int e = gtid; e < N_EDGES; e += BUILD_THREADS) {
        int p = atomicAdd(&cursor[dst[e]], 1);
        ebuf[p] = src[e];
    }
}

// ---------------- fused gather + MFMA layer ----------------
// Block = 256 threads = 16 nodes. Phase 1: thread (nl=t>>4,q=t&15) accumulates
// mean of node node0+nl cols [8q,8q+8) (fp32), 8-deep load batches for MLP,
// bf16 result -> LDS tile. Phase 2: wave wv does feats [32wv,32wv+32) via
// 16x16x32 bf16 MFMA; A(mean) from LDS, A(x)/B(W) from global (R6-validated).
template <bool RELU, bool OUT_BF16>
__global__ void __launch_bounds__(256) k_gather_layer(
    const int* __restrict__ off, const int* __restrict__ ebuf,
    const unsigned short* __restrict__ Xbf,
    const unsigned short* __restrict__ Wlbf, const float* __restrict__ bias,
    const unsigned short* __restrict__ Wrbf, void* __restrict__ outp) {
    __shared__ unsigned short tile[16][136];

    const int t = threadIdx.x;
    const int node0 = blockIdx.x * 16;

    {
        const int nl = t >> 4, q = t & 15;
        const int node = node0 + nl;
        int s0 = off[node], s1 = off[node + 1];
        float acc[8] = {0.f, 0.f, 0.f, 0.f, 0.f, 0.f, 0.f, 0.f};
        int e = s0;
        for (; e + 8 <= s1; e += 8) {
            uint4 w[8];
#pragma unroll
            for (int j = 0; j < 8; ++j)
                w[j] = *(const uint4*)(Xbf + (size_t)ebuf[e + j] * D + q * 8);
#pragma unroll
            for (int j = 0; j < 8; ++j) {
                acc[0] += bf_lo(w[j].x); acc[1] += bf_hi(w[j].x);
                acc[2] += bf_lo(w[j].y); acc[3] += bf_hi(w[j].y);
                acc[4] += bf_lo(w[j].z); acc[5] += bf_hi(w[j].z);
                acc[6] += bf_lo(w[j].w); acc[7] += bf_hi(w[j].w);
            }
        }
        for (; e + 4 <= s1; e += 4) {
            uint4 w[4];
#pragma unroll
            for (int j = 0; j < 4; ++j)
                w[j] = *(const uint4*)(Xbf + (size_t)ebuf[e + j] * D + q * 8);
#pragma unroll
            for (int j = 0; j < 4; ++j) {
                acc[0] += bf_lo(w[j].x); acc[1] += bf_hi(w[j].x);
                acc[2] += bf_lo(w[j].y); acc[3] += bf_hi(w[j].y);
                acc[4] += bf_lo(w[j].z); acc[5] += bf_hi(w[j].z);
                acc[6] += bf_lo(w[j].w); acc[7] += bf_hi(w[j].w);
            }
        }
        for (; e < s1; ++e) {
            uint4 va = *(const uint4*)(Xbf + (size_t)ebuf[e] * D + q * 8);
            acc[0] += bf_lo(va.x); acc[1] += bf_hi(va.x);
            acc[2] += bf_lo(va.y); acc[3] += bf_hi(va.y);
            acc[4] += bf_lo(va.z); acc[5] += bf_hi(va.z);
            acc[6] += bf_lo(va.w); acc[7] += bf_hi(va.w);
        }
        float inv = (s1 > s0) ? 1.0f / (float)(s1 - s0) : 0.0f;
        uint4 o;
        o.x = f2bf(acc[0] * inv) | (f2bf(acc[1] * inv) << 16);
        o.y = f2bf(acc[2] * inv) | (f2bf(acc[3] * inv) << 16);
        o.z = f2bf(acc[4] * inv) | (f2bf(acc[5] * inv) << 16);
        o.w = f2bf(acc[6] * inv) | (f2bf(acc[7] * inv) << 16);
        *(uint4*)(&tile[nl][q * 8]) = o;
    }
    __syncthreads();

    const int lane = t & 63;
    const int wv = t >> 6;
    const int l15 = lane & 15;
    const int quad = lane >> 4;

    floatx4 c0 = (floatx4)(0.f), c1 = (floatx4)(0.f);
    const int nf0 = wv * 2, nf1 = wv * 2 + 1;

    const unsigned short* mrow = &tile[l15][quad * 8];
    const unsigned short* arowX = Xbf + (size_t)(node0 + l15) * D + quad * 8;

#pragma unroll
    for (int kk = 0; kk < 4; ++kk) {
        bf16x8 a = *(const bf16x8*)(mrow + kk * 32);
        bf16x8 b0 = *(const bf16x8*)(Wlbf + (size_t)(nf0 * 16 + l15) * D + kk * 32 + quad * 8);
        bf16x8 b1 = *(const bf16x8*)(Wlbf + (size_t)(nf1 * 16 + l15) * D + kk * 32 + quad * 8);
        c0 = __builtin_amdgcn_mfma_f32_16x16x32_bf16(a, b0, c0, 0, 0, 0);
        c1 = __builtin_amdgcn_mfma_f32_16x16x32_bf16(a, b1, c1, 0, 0, 0);
    }
#pragma unroll
    for (int kk = 0; kk < 4; ++kk) {
        bf16x8 a = *(const bf16x8*)(arowX + kk * 32);
        bf16x8 b0 = *(const bf16x8*)(Wrbf + (size_t)(nf0 * 16 + l15) * D + kk * 32 + quad * 8);
        bf16x8 b1 = *(const bf16x8*)(Wrbf + (size_t)(nf1 * 16 + l15) * D + kk * 32 + quad * 8);
        c0 = __builtin_amdgcn_mfma_f32_16x16x32_bf16(a, b0, c0, 0, 0, 0);
        c1 = __builtin_amdgcn_mfma_f32_16x16x32_bf16(a, b1, c1, 0, 0, 0);
    }

#pragma unroll
    for (int j = 0; j < 2; ++j) {
        floatx4 c = j ? c1 : c0;
        int f = (wv * 2 + j) * 16 + l15;
        float bv = bias[f];
#pragma unroll
        for (int r = 0; r < 4; ++r) {
            float v = c[r] + bv;
            if (RELU) v = v > 0.f ? v : 0.2f * v;
            int node = node0 + quad * 4 + r;
            if (OUT_BF16)
                ((unsigned short*)outp)[(size_t)node * D + f] = (unsigned short)f2bf(v);
            else
                ((float*)outp)[(size_t)node * D + f] = v;
        }
    }
}

// ---------------- host launch ----------------

extern "C" void kernel_launch(void* const* d_in, const int* in_sizes, int n_in,
                              void* d_out, int out_size, void* d_ws, size_t ws_size,
                              hipStream_t stream) {
    (void)in_sizes; (void)n_in; (void)out_size; (void)ws_size;

    const float* x   = (const float*)d_in[0];
    const int*   ei  = (const int*)d_in[1];
    const float* W1l = (const float*)d_in[2];
    const float* b1  = (const float*)d_in[3];
    const float* W1r = (const float*)d_in[4];
    const float* W2l = (const float*)d_in[5];
    const float* b2  = (const float*)d_in[6];
    const float* W2r = (const float*)d_in[7];

    const int* src = ei;
    const int* dst = ei + N_EDGES;

    char* ws = (char*)d_ws;
    int*   cnt     = (int*)(ws + 0);                 // 200,000 B
    int*   off     = (int*)(ws + 200064);            // 200,004 B
    int*   cursor  = (int*)(ws + 400128);            // 200,000 B
    int*   partial = (int*)(ws + 600192);            // 2,048 B
    int*   ebuf    = (int*)(ws + 602240);            // 2,400,000 B
    unsigned short* wbf = (unsigned short*)(ws + 3002240);   // 131,072 B
    unsigned short* xbf = (unsigned short*)(ws + 3133312);   // 12,800,000 B
    unsigned short* hbf = (unsigned short*)(ws + 15933312);  // 12,800,000 B
    float* out = (float*)d_out;

    unsigned short* w1l_bf = wbf;
    unsigned short* w1r_bf = wbf + 16384;
    unsigned short* w2l_bf = wbf + 32768;
    unsigned short* w2r_bf = wbf + 49152;

    void* args[] = {
        (void*)&x, (void*)&xbf,
        (void*)&W1l, (void*)&W1r, (void*)&W2l, (void*)&W2r, (void*)&wbf,
        (void*)&src, (void*)&dst,
        (void*)&cnt, (void*)&off, (void*)&cursor, (void*)&partial, (void*)&ebuf
    };
    hipLaunchCooperativeKernel((void*)k_build, dim3(BUILD_BLOCKS), dim3(256),
                               args, 0, stream);

    k_gather_layer<true, true><<<N_NODES / 16, 256, 0, stream>>>(
        off, ebuf, xbf, w1l_bf, b1, w1r_bf, (void*)hbf);
    k_gather_layer<false, false><<<N_NODES / 16, 256, 0, stream>>>(
        off, ebuf, hbf, w2l_bf, b2, w2r_bf, (void*)out);
}